// Round 1
// baseline (78.577 us; speedup 1.0000x reference)
//
#include <hip/hip_runtime.h>
#include <stdint.h>

// Problem constants (match reference)
#define BATCH 8192
#define NREF  2048
#define DIM   256

#define WORDS64 (DIM / 64)              // 4 uint64 per row
#define S_WORDS (BATCH * WORDS64)       // 32768
#define R_WORDS (NREF * WORDS64)        // 8192
#define TOT_WORDS (S_WORDS + R_WORDS)   // 40960

// Main-kernel tiling
#define CHUNK  64                       // refs per block
#define NCHUNK (NREF / CHUNK)           // 32
#define TPB    256                      // threads per block
#define BPT    2                        // batch rows per thread
#define BPB    (TPB * BPT)              // 512 batch rows per block
#define NBBLK  (BATCH / BPB)            // 16

// ---------------------------------------------------------------------------
// Kernel 1: bit-pack states and R. Each 64-lane wave reads 64 consecutive
// floats (coalesced 4B/lane) and emits one uint64 via __ballot.
// ---------------------------------------------------------------------------
__global__ void pack_kernel(const float* __restrict__ states,
                            const float* __restrict__ R,
                            unsigned long long* __restrict__ sp,
                            unsigned long long* __restrict__ rp) {
    const int lane = threadIdx.x & 63;
    int gw = (blockIdx.x * blockDim.x + threadIdx.x) >> 6;   // global wave id
    const int nw = (gridDim.x * blockDim.x) >> 6;
    for (int w = gw; w < TOT_WORDS; w += nw) {
        const float* src;
        unsigned long long* dst;
        int idx;
        if (w < S_WORDS) { src = states; dst = sp; idx = w; }
        else             { src = R;      dst = rp; idx = w - S_WORDS; }
        const float f = src[(size_t)idx * 64 + lane];
        const unsigned long long m = __ballot(f > 0.5f);
        if (lane == 0) dst[idx] = m;
    }
}

// ---------------------------------------------------------------------------
// Kernel 2: hamming-min. Block (chunk, bblk): stage 64 refs (2 KB, packed)
// into LDS; each thread owns 2 batch rows in registers and scans the chunk.
// LDS reads are wave-uniform -> broadcast, no bank conflicts.
// ---------------------------------------------------------------------------
__global__ __launch_bounds__(TPB) void hamming_kernel(
        const uint4* __restrict__ sp,      // [BATCH][2] packed states
        const uint4* __restrict__ rp,      // [NREF][2]  packed refs
        int* __restrict__ partial) {       // [NCHUNK][BATCH]
    __shared__ uint4 lds[CHUNK * 2];       // 64 refs x 32B = 2 KB

    const int chunk = blockIdx.x;
    const int bblk  = blockIdx.y;
    const int t     = threadIdx.x;

    if (t < CHUNK * 2) lds[t] = rp[chunk * (CHUNK * 2) + t];
    __syncthreads();

    const int b0 = bblk * BPB + t;
    const int b1 = b0 + TPB;

    const uint4 sa0 = sp[2 * b0], sa1 = sp[2 * b0 + 1];
    const uint4 sb0 = sp[2 * b1], sb1 = sp[2 * b1 + 1];

    int m0 = 0x7fffffff, m1 = 0x7fffffff;

#pragma unroll 8
    for (int r = 0; r < CHUNK; ++r) {
        const uint4 r0 = lds[2 * r];
        const uint4 r1 = lds[2 * r + 1];
        int h0 = __popc(r0.x ^ sa0.x) + __popc(r0.y ^ sa0.y)
               + __popc(r0.z ^ sa0.z) + __popc(r0.w ^ sa0.w)
               + __popc(r1.x ^ sa1.x) + __popc(r1.y ^ sa1.y)
               + __popc(r1.z ^ sa1.z) + __popc(r1.w ^ sa1.w);
        int h1 = __popc(r0.x ^ sb0.x) + __popc(r0.y ^ sb0.y)
               + __popc(r0.z ^ sb0.z) + __popc(r0.w ^ sb0.w)
               + __popc(r1.x ^ sb1.x) + __popc(r1.y ^ sb1.y)
               + __popc(r1.z ^ sb1.z) + __popc(r1.w ^ sb1.w);
        m0 = min(m0, h0);
        m1 = min(m1, h1);
    }

    partial[chunk * BATCH + b0] = m0;
    partial[chunk * BATCH + b1] = m1;
}

// ---------------------------------------------------------------------------
// Kernel 3: reduce 32 per-chunk partial mins -> float output.
// ---------------------------------------------------------------------------
__global__ void reduce_kernel(const int* __restrict__ partial,
                              float* __restrict__ out) {
    const int b = blockIdx.x * blockDim.x + threadIdx.x;
    int m = partial[b];
#pragma unroll
    for (int c = 1; c < NCHUNK; ++c) m = min(m, partial[c * BATCH + b]);
    out[b] = (float)m;
}

// ---------------------------------------------------------------------------
extern "C" void kernel_launch(void* const* d_in, const int* in_sizes, int n_in,
                              void* d_out, int out_size, void* d_ws, size_t ws_size,
                              hipStream_t stream) {
    const float* states = (const float*)d_in[0];   // [8192, 256] fp32 (0/1)
    const float* R      = (const float*)d_in[1];   // [2048, 256] fp32 (0/1)
    float* out          = (float*)d_out;           // [8192] fp32

    char* ws = (char*)d_ws;
    unsigned long long* sp64 = (unsigned long long*)ws;              // 256 KB
    unsigned long long* rp64 = (unsigned long long*)(ws + 262144);   //  64 KB
    int* partial             = (int*)(ws + 262144 + 65536);          //   1 MB

    // 1) pack: 2560 waves, grid-stride over 40960 words
    pack_kernel<<<640, 256, 0, stream>>>(states, R, sp64, rp64);

    // 2) hamming-min: 32 chunk-blocks x 16 batch-blocks
    dim3 grid(NCHUNK, NBBLK);
    hamming_kernel<<<grid, TPB, 0, stream>>>((const uint4*)sp64,
                                             (const uint4*)rp64, partial);

    // 3) reduce partial mins -> float out
    reduce_kernel<<<BATCH / 256, 256, 0, stream>>>(partial, out);
}

// Round 2
// 69.199 us; speedup vs baseline: 1.1355x; 1.1355x over previous
//
#include <hip/hip_runtime.h>
#include <stdint.h>

// Problem constants (match reference)
#define BATCH 8192
#define NREF  2048
#define DIM   256

// Packed layout: 32 bytes (256 bits) per row
#define SBYTES (BATCH * 32)            // 262144 bytes
#define RBYTES (NREF * 32)             //  65536 bytes
#define TOTB   (SBYTES + RBYTES)       // 327680 bytes (one thread packs one byte)

// Main-kernel tiling
#define CHUNK  64                      // refs per block
#define NCHUNK (NREF / CHUNK)          // 32
#define TPB    256                     // threads per block
#define BPT    2                       // batch rows per thread
#define BPB    (TPB * BPT)             // 512 batch rows per block
#define NBBLK  (BATCH / BPB)           // 16

// ---------------------------------------------------------------------------
// Kernel 1: bit-pack states and R (one thread = 8 floats -> 1 byte), and
// initialize d_out to +INF so the hamming kernel can atomicMin into it.
// Bit order within a byte/row is arbitrary but identical for s and R, which
// is all hamming distance needs.
// ---------------------------------------------------------------------------
__global__ __launch_bounds__(256) void pack_init_kernel(
        const float* __restrict__ states,
        const float* __restrict__ R,
        uint8_t* __restrict__ sp,
        uint8_t* __restrict__ rp,
        float* __restrict__ out) {
    const int gid = blockIdx.x * blockDim.x + threadIdx.x;   // 0 .. TOTB-1

    if (gid < BATCH) out[gid] = __int_as_float(0x7f800000);  // +inf

    const float4* src;
    uint8_t* dst;
    int idx;
    if (gid < SBYTES) { src = (const float4*)states; dst = sp; idx = gid; }
    else              { src = (const float4*)R;      dst = rp; idx = gid - SBYTES; }

    const float4 v0 = src[idx * 2];
    const float4 v1 = src[idx * 2 + 1];
    unsigned int b = 0;
    b |= (v0.x > 0.5f) ? 0x01u : 0u;
    b |= (v0.y > 0.5f) ? 0x02u : 0u;
    b |= (v0.z > 0.5f) ? 0x04u : 0u;
    b |= (v0.w > 0.5f) ? 0x08u : 0u;
    b |= (v1.x > 0.5f) ? 0x10u : 0u;
    b |= (v1.y > 0.5f) ? 0x20u : 0u;
    b |= (v1.z > 0.5f) ? 0x40u : 0u;
    b |= (v1.w > 0.5f) ? 0x80u : 0u;
    dst[idx] = (uint8_t)b;
}

// ---------------------------------------------------------------------------
// Kernel 2: hamming-min. Block (chunk, bblk): stage 64 packed refs (2 KB) in
// LDS; each thread owns 2 batch rows in registers, scans the chunk, then
// atomicMin's the float-bits of its min into d_out. Distances are nonneg ints
// <= 256, so int-compare on float bit patterns == float compare, exactly.
// ---------------------------------------------------------------------------
__global__ __launch_bounds__(TPB) void hamming_kernel(
        const uint4* __restrict__ sp,      // [BATCH][2] packed states
        const uint4* __restrict__ rp,      // [NREF][2]  packed refs
        float* __restrict__ out) {         // [BATCH], pre-inited to +inf
    __shared__ uint4 lds[CHUNK * 2];       // 64 refs x 32 B = 2 KB

    const int chunk = blockIdx.x;
    const int bblk  = blockIdx.y;
    const int t     = threadIdx.x;

    if (t < CHUNK * 2) lds[t] = rp[chunk * (CHUNK * 2) + t];
    __syncthreads();

    const int b0 = bblk * BPB + t;
    const int b1 = b0 + TPB;

    const uint4 sa0 = sp[2 * b0], sa1 = sp[2 * b0 + 1];
    const uint4 sb0 = sp[2 * b1], sb1 = sp[2 * b1 + 1];

    int m0 = 0x7fffffff, m1 = 0x7fffffff;

#pragma unroll 8
    for (int r = 0; r < CHUNK; ++r) {
        const uint4 r0 = lds[2 * r];
        const uint4 r1 = lds[2 * r + 1];
        int h0 = __popc(r0.x ^ sa0.x) + __popc(r0.y ^ sa0.y)
               + __popc(r0.z ^ sa0.z) + __popc(r0.w ^ sa0.w)
               + __popc(r1.x ^ sa1.x) + __popc(r1.y ^ sa1.y)
               + __popc(r1.z ^ sa1.z) + __popc(r1.w ^ sa1.w);
        int h1 = __popc(r0.x ^ sb0.x) + __popc(r0.y ^ sb0.y)
               + __popc(r0.z ^ sb0.z) + __popc(r0.w ^ sb0.w)
               + __popc(r1.x ^ sb1.x) + __popc(r1.y ^ sb1.y)
               + __popc(r1.z ^ sb1.z) + __popc(r1.w ^ sb1.w);
        m0 = min(m0, h0);
        m1 = min(m1, h1);
    }

    // nonneg float bit patterns are int-ordered -> atomicMin on int is exact
    atomicMin((int*)&out[b0], __float_as_int((float)m0));
    atomicMin((int*)&out[b1], __float_as_int((float)m1));
}

// ---------------------------------------------------------------------------
extern "C" void kernel_launch(void* const* d_in, const int* in_sizes, int n_in,
                              void* d_out, int out_size, void* d_ws, size_t ws_size,
                              hipStream_t stream) {
    const float* states = (const float*)d_in[0];   // [8192, 256] fp32 (0/1)
    const float* R      = (const float*)d_in[1];   // [2048, 256] fp32 (0/1)
    float* out          = (float*)d_out;           // [8192] fp32

    char* ws = (char*)d_ws;
    uint8_t* sp = (uint8_t*)ws;                    // 256 KB packed states
    uint8_t* rp = (uint8_t*)(ws + SBYTES);         //  64 KB packed refs

    // 1) pack both inputs + init out to +inf (stream-ordered before kernel 2)
    pack_init_kernel<<<TOTB / 256, 256, 0, stream>>>(states, R, sp, rp, out);

    // 2) hamming-min with atomicMin epilogue straight into d_out
    dim3 grid(NCHUNK, NBBLK);
    hamming_kernel<<<grid, TPB, 0, stream>>>((const uint4*)sp,
                                             (const uint4*)rp, out);
}